// Round 2
// baseline (3677.474 us; speedup 1.0000x reference)
//
#include <hip/hip_runtime.h>

#define T_STEPS 512
#define BATCH   256

typedef _Float16 f16;
typedef __attribute__((ext_vector_type(8))) _Float16 f16x8;
typedef __attribute__((ext_vector_type(4))) _Float16 f16x4;
typedef __attribute__((ext_vector_type(4))) float    f32x4;

__device__ __forceinline__ float sigmoid_f(float x) {
    return 1.0f / (1.0f + __expf(-x));
}
__device__ __forceinline__ float tanh_f(float x) {
    // 1 - 2/(e^{2x}+1): monotone, no NaN for large |x|
    return 1.0f - 2.0f / (__expf(2.0f * x) + 1.0f);
}

// One block per 16 batch elements (grid = 16). Wave w owns units [16w,16w+16)
// of ALL FOUR gates: per step it does 4 gate-C-tiles of 16x16 via
// mfma_f32_16x16x32_f16 over K = IN_DIM + H (x-projection folded in).
// B-fragments (weights, f16) are step-invariant -> live in VGPRs.
// A-panels (x_t, h) go through LDS f16, double-buffered, 1 barrier/step.
// C-layout (verified m89): col = lane&15 (unit), row = 4*(lane>>4)+reg (batch)
// -> i,f,g,o of one unit land in the same lane; c stays in registers.
template <int IN_DIM, int H, bool APPLY_TANH>
__global__ __launch_bounds__(4 * H, 1)
void lstm_mfma(const float* __restrict__ x,      // [T, B, IN_DIM]
               const float* __restrict__ w_ih,   // [4H, IN_DIM]
               const float* __restrict__ w_hh,   // [4H, H]
               const float* __restrict__ b_ih,   // [4H]
               const float* __restrict__ b_hh,   // [4H]
               float* __restrict__ out)          // [T, B, H]
{
    constexpr int KTX = IN_DIM / 32;   // K-tiles from input projection
    constexpr int KTH = H / 32;        // K-tiles from recurrence
    constexpr int KT  = KTX + KTH;
    constexpr int XP  = IN_DIM + 8;    // +8 f16 pad: row stride = K*2+16 B -> 2-way-max bank aliasing
    constexpr int HP  = H + 8;
    constexpr int NTHREADS = 4 * H;

    __shared__ f16 xs[2][16][XP];
    __shared__ f16 hs[2][16][HP];

    const int tid  = threadIdx.x;
    const int wave = tid >> 6;
    const int lane = tid & 63;
    const int col  = lane & 15;        // n within tile = unit offset
    const int q    = lane >> 4;        // quad: k-group for A/B frags, row-group for C
    const int bblk = blockIdx.x * 16;  // batch base
    const int u    = wave * 16 + col;  // this lane's unit

    // ---- one-time: load this wave's B-fragments (weights) into registers ----
    // B-frag layout (symmetric to A, m120-verified A[m=lane&15][k=quad*8+j]):
    // lane supplies B[k = kt*32 + quad*8 + j][n = lane&15]; W rows are [n][k]
    // row-major so the 8 k's are contiguous fp32 -> convert to f16 once.
    f16x8 bw[4][KT];
#pragma unroll
    for (int g = 0; g < 4; ++g) {
        const int row = g * H + u;
#pragma unroll
        for (int kt = 0; kt < KTX; ++kt) {
            const float* p = w_ih + (size_t)row * IN_DIM + kt * 32 + q * 8;
            f16x8 v;
#pragma unroll
            for (int j = 0; j < 8; ++j) v[j] = (f16)p[j];
            bw[g][kt] = v;
        }
#pragma unroll
        for (int kt = 0; kt < KTH; ++kt) {
            const float* p = w_hh + (size_t)row * H + kt * 32 + q * 8;
            f16x8 v;
#pragma unroll
            for (int j = 0; j < 8; ++j) v[j] = (f16)p[j];
            bw[g][KTX + kt] = v;
        }
    }
    float bias[4];
#pragma unroll
    for (int g = 0; g < 4; ++g) bias[g] = b_ih[g * H + u] + b_hh[g * H + u];

    float c[4] = {0.f, 0.f, 0.f, 0.f};   // cell state, register-resident

    // stage x[t] (fp32 global -> f16 LDS), float4-vectorized
    auto stage_x = [&](int t, int buf) {
        constexpr int N4 = 16 * IN_DIM / 4;
        for (int idx = tid; idx < N4; idx += NTHREADS) {
            const int b  = idx / (IN_DIM / 4);
            const int i4 = idx % (IN_DIM / 4);
            const f32x4 v = *reinterpret_cast<const f32x4*>(
                x + ((size_t)t * BATCH + bblk + b) * IN_DIM + 4 * i4);
            f16x4 h4;
            h4[0] = (f16)v[0]; h4[1] = (f16)v[1]; h4[2] = (f16)v[2]; h4[3] = (f16)v[3];
            *reinterpret_cast<f16x4*>(&xs[buf][b][4 * i4]) = h4;
        }
    };

    // init: h(0) = 0, stage x(0)
    for (int idx = tid; idx < 16 * HP; idx += NTHREADS)
        hs[0][idx / HP][idx % HP] = (f16)0.f;
    stage_x(0, 0);
    __syncthreads();

    int pb = 0;
    for (int t = 0; t < T_STEPS; ++t) {
        // ---- A-fragments from LDS: A[m = lane&15][k = quad*8 + j] ----
        f16x8 a[KT];
#pragma unroll
        for (int kt = 0; kt < KTX; ++kt)
            a[kt] = *reinterpret_cast<const f16x8*>(&xs[pb][col][kt * 32 + q * 8]);
#pragma unroll
        for (int kt = 0; kt < KTH; ++kt)
            a[KTX + kt] = *reinterpret_cast<const f16x8*>(&hs[pb][col][kt * 32 + q * 8]);

        // ---- MFMA: 4 gate accumulators, bias-initialized ----
        f32x4 acc[4];
#pragma unroll
        for (int g = 0; g < 4; ++g)
            acc[g] = (f32x4){bias[g], bias[g], bias[g], bias[g]};
#pragma unroll
        for (int kt = 0; kt < KT; ++kt)
#pragma unroll
            for (int g = 0; g < 4; ++g)
                acc[g] = __builtin_amdgcn_mfma_f32_16x16x32_f16(a[kt], bw[g][kt], acc[g], 0, 0, 0);

        // prefetch next step's x into the other buffer (latency hidden by the
        // nonlinearity + barrier below)
        if (t + 1 < T_STEPS) stage_x(t + 1, 1 - pb);

        // ---- gates -> c,h (all in-register; lane owns 4 (batch,unit) cells) ----
#pragma unroll
        for (int r = 0; r < 4; ++r) {
            const int m = q * 4 + r;   // batch row (C-layout)
            const float gi = acc[0][r];
            const float gf = acc[1][r];
            const float gg = acc[2][r];
            const float go = acc[3][r];
            c[r] = sigmoid_f(gf) * c[r] + sigmoid_f(gi) * tanh_f(gg);
            const float h = sigmoid_f(go) * tanh_f(c[r]);
            hs[1 - pb][m][u] = (f16)h;   // recurrent h (un-tanh'd even for L2)
            out[((size_t)t * BATCH + bblk + m) * H + u] = APPLY_TANH ? tanh_f(h) : h;
        }
        __syncthreads();
        pb ^= 1;
    }
}

extern "C" void kernel_launch(void* const* d_in, const int* in_sizes, int n_in,
                              void* d_out, int out_size, void* d_ws, size_t ws_size,
                              hipStream_t stream) {
    const float* X     = (const float*)d_in[0];
    const float* w1_ih = (const float*)d_in[1];
    const float* w1_hh = (const float*)d_in[2];
    const float* b1_ih = (const float*)d_in[3];
    const float* b1_hh = (const float*)d_in[4];
    const float* w2_ih = (const float*)d_in[5];
    const float* w2_hh = (const float*)d_in[6];
    const float* b2_ih = (const float*)d_in[7];
    const float* b2_hh = (const float*)d_in[8];
    const float* w3_ih = (const float*)d_in[9];
    const float* w3_hh = (const float*)d_in[10];
    const float* b3_ih = (const float*)d_in[11];
    const float* b3_hh = (const float*)d_in[12];
    const float* w4_ih = (const float*)d_in[13];
    const float* w4_hh = (const float*)d_in[14];
    const float* b4_ih = (const float*)d_in[15];
    const float* b4_hh = (const float*)d_in[16];

    float* out = (float*)d_out;

    // workspace: h1 [512,256,128] fp32 (reused for h3), h2 [512,256,32] fp32
    float* h1 = (float*)d_ws;
    float* h2 = h1 + (size_t)T_STEPS * BATCH * 128;

    constexpr int GRID = BATCH / 16;

    // layer 1: 64 -> 128
    lstm_mfma<64, 128, false><<<GRID, 512, 0, stream>>>(X, w1_ih, w1_hh, b1_ih, b1_hh, h1);
    // layer 2: 128 -> 32, bottleneck tanh on the forwarded output only
    lstm_mfma<128, 32, true><<<GRID, 128, 0, stream>>>(h1, w2_ih, w2_hh, b2_ih, b2_hh, h2);
    // layer 3: 32 -> 128 (h1's contents already consumed; reuse)
    lstm_mfma<32, 128, false><<<GRID, 512, 0, stream>>>(h2, w3_ih, w3_hh, b3_ih, b3_hh, h1);
    // layer 4: 128 -> 64 -> d_out
    lstm_mfma<128, 64, false><<<GRID, 256, 0, stream>>>(h1, w4_ih, w4_hh, b4_ih, b4_hh, out);
}

// Round 3
// 2788.353 us; speedup vs baseline: 1.3189x; 1.3189x over previous
//
#include <hip/hip_runtime.h>

#define T_STEPS 512
#define BATCH   256

typedef _Float16 f16;
typedef __attribute__((ext_vector_type(8))) _Float16 f16x8;
typedef __attribute__((ext_vector_type(4))) _Float16 f16x4;
typedef __attribute__((ext_vector_type(4))) float    f32x4;

__device__ __forceinline__ float sigmoid_f(float x) {
    return 1.0f / (1.0f + __expf(-x));
}
__device__ __forceinline__ float tanh_f(float x) {
    return 1.0f - 2.0f / (__expf(2.0f * x) + 1.0f);
}

// Barrier that only waits for LDS ops (lgkmcnt), NOT global loads/stores.
// __syncthreads() would emit s_waitcnt vmcnt(0) and put global-store/load
// latency on the per-step critical path (m97 barrier-drain).
__device__ __forceinline__ void barrier_lds_only() {
    asm volatile("s_waitcnt lgkmcnt(0)\n\ts_barrier" ::: "memory");
}

// One block per 16 batch elements (grid = 16). Wave w owns units [16w,16w+16)
// of all four gates; per step: 4 gate C-tiles (16x16) via mfma_f32_16x16x32_f16
// over K = IN_DIM + H. Weights (B-frags, f16) are step-invariant in VGPRs.
// x_t / h go through double-buffered f16 LDS panels; ONE lds-only barrier/step.
// x(t+1) is prefetched into registers at the top of step t and committed to
// LDS at the bottom, hiding global latency under MFMA + gate math.
template <int IN_DIM, int H, bool IN_F16, bool OUT_F16, bool APPLY_TANH>
__global__ __launch_bounds__(4 * H, 1)
void lstm_mfma(const void* __restrict__ xv,
               const float* __restrict__ w_ih,   // [4H, IN_DIM]
               const float* __restrict__ w_hh,   // [4H, H]
               const float* __restrict__ b_ih,   // [4H]
               const float* __restrict__ b_hh,   // [4H]
               void* __restrict__ outv)          // [T, B, H] (f16 or f32)
{
    constexpr int KTX = IN_DIM / 32;
    constexpr int KTH = H / 32;
    constexpr int KT  = KTX + KTH;
    constexpr int XP  = IN_DIM + 8;    // +16B pad: keeps rows 16B-aligned, odd 16B stride
    constexpr int HP  = H + 8;
    constexpr int NT  = 4 * H;
    constexpr int XBYTES = 16 * IN_DIM * (IN_F16 ? 2 : 4);
    constexpr int NCH = XBYTES / 16;               // 16B chunks per timestep panel
    constexpr int CPT = (NCH + NT - 1) / NT;       // chunks per thread

    __shared__ f16 xs[2][16][XP];
    __shared__ f16 hs[2][16][HP];

    const int tid  = threadIdx.x;
    const int wave = tid >> 6;
    const int lane = tid & 63;
    const int col  = lane & 15;
    const int q    = lane >> 4;
    const int bblk = blockIdx.x * 16;
    const int u    = wave * 16 + col;

    // ---- one-time: B-fragments (weights) -> registers ----
    // lane supplies B[k = kt*32 + q*8 + j][n = col]; W rows are [n][k] row-major.
    f16x8 bw[4][KT];
#pragma unroll
    for (int g = 0; g < 4; ++g) {
        const int row = g * H + u;
#pragma unroll
        for (int kt = 0; kt < KTX; ++kt) {
            const float* p = w_ih + (size_t)row * IN_DIM + kt * 32 + q * 8;
            f16x8 v;
#pragma unroll
            for (int j = 0; j < 8; ++j) v[j] = (f16)p[j];
            bw[g][kt] = v;
        }
#pragma unroll
        for (int kt = 0; kt < KTH; ++kt) {
            const float* p = w_hh + (size_t)row * H + kt * 32 + q * 8;
            f16x8 v;
#pragma unroll
            for (int j = 0; j < 8; ++j) v[j] = (f16)p[j];
            bw[g][KTX + kt] = v;
        }
    }
    float bias[4];
#pragma unroll
    for (int g = 0; g < 4; ++g) bias[g] = b_ih[g * H + u] + b_hh[g * H + u];

    float cst[4] = {0.f, 0.f, 0.f, 0.f};

    // commit helpers: chunk index -> padded LDS location
    auto commit16 = [&](int buf, int cc, f16x8 v) {
        constexpr int EPR = IN_DIM / 8;            // f16x8 chunks per row
        const int row = cc / EPR, off = cc % EPR;
        *reinterpret_cast<f16x8*>(&xs[buf][row][off * 8]) = v;
    };
    auto commit32 = [&](int buf, int cc, f32x4 v) {
        constexpr int EPR = IN_DIM / 4;            // f32x4 chunks per row
        const int row = cc / EPR, off = cc % EPR;
        f16x4 h4;
        h4[0] = (f16)v[0]; h4[1] = (f16)v[1]; h4[2] = (f16)v[2]; h4[3] = (f16)v[3];
        *reinterpret_cast<f16x4*>(&xs[buf][row][off * 4]) = h4;
    };

    // ---- init: h(0) = 0, stage x(0) synchronously ----
    for (int i = tid; i < 16 * HP; i += NT) hs[0][i / HP][i % HP] = (f16)0.f;
    if constexpr (IN_F16) {
        const f16x8* g = (const f16x8*)((const f16*)xv + (size_t)bblk * IN_DIM);
#pragma unroll
        for (int k = 0; k < CPT; ++k) {
            const int cc = tid + k * NT;
            if (cc < NCH) commit16(0, cc, g[cc]);
        }
    } else {
        const f32x4* g = (const f32x4*)((const float*)xv + (size_t)bblk * IN_DIM);
#pragma unroll
        for (int k = 0; k < CPT; ++k) {
            const int cc = tid + k * NT;
            if (cc < NCH) commit32(0, cc, g[cc]);
        }
    }
    __syncthreads();

    int pb = 0;
    for (int t = 0; t < T_STEPS; ++t) {
        // ---- issue x(t+1) prefetch loads into registers (latency hidden below) ----
        f16x8 xr16[CPT];
        f32x4 xr32[CPT];
        const bool pf = (t + 1 < T_STEPS);
        if (pf) {
            if constexpr (IN_F16) {
                const f16x8* g = (const f16x8*)((const f16*)xv +
                                 ((size_t)(t + 1) * BATCH + bblk) * IN_DIM);
#pragma unroll
                for (int k = 0; k < CPT; ++k) {
                    const int cc = tid + k * NT;
                    if (cc < NCH) xr16[k] = g[cc];
                }
            } else {
                const f32x4* g = (const f32x4*)((const float*)xv +
                                 ((size_t)(t + 1) * BATCH + bblk) * IN_DIM);
#pragma unroll
                for (int k = 0; k < CPT; ++k) {
                    const int cc = tid + k * NT;
                    if (cc < NCH) xr32[k] = g[cc];
                }
            }
        }

        // ---- A-fragments from LDS ----
        f16x8 a[KT];
#pragma unroll
        for (int kt = 0; kt < KTX; ++kt)
            a[kt] = *reinterpret_cast<const f16x8*>(&xs[pb][col][kt * 32 + q * 8]);
#pragma unroll
        for (int kt = 0; kt < KTH; ++kt)
            a[KTX + kt] = *reinterpret_cast<const f16x8*>(&hs[pb][col][kt * 32 + q * 8]);

        // ---- MFMA: 4 gate accumulators ----
        f32x4 acc[4];
#pragma unroll
        for (int g = 0; g < 4; ++g)
            acc[g] = (f32x4){bias[g], bias[g], bias[g], bias[g]};
#pragma unroll
        for (int kt = 0; kt < KT; ++kt)
#pragma unroll
            for (int g = 0; g < 4; ++g)
                acc[g] = __builtin_amdgcn_mfma_f32_16x16x32_f16(a[kt], bw[g][kt], acc[g], 0, 0, 0);

        // ---- gates -> c,h; write h to LDS and layer output to global ----
#pragma unroll
        for (int r = 0; r < 4; ++r) {
            const int m = q * 4 + r;   // batch row (C-layout: col=lane&15, row=4q+r)
            const float gi = acc[0][r];
            const float gf = acc[1][r];
            const float gg = acc[2][r];
            const float go = acc[3][r];
            cst[r] = sigmoid_f(gf) * cst[r] + sigmoid_f(gi) * tanh_f(gg);
            const float h = sigmoid_f(go) * tanh_f(cst[r]);
            hs[1 - pb][m][u] = (f16)h;
            const float ov = APPLY_TANH ? tanh_f(h) : h;
            const size_t oidx = ((size_t)t * BATCH + bblk + m) * H + u;
            if constexpr (OUT_F16) ((f16*)outv)[oidx] = (f16)ov;
            else                   ((float*)outv)[oidx] = ov;
        }

        // ---- commit x(t+1) to LDS (vmcnt wait lands here, mostly hidden) ----
        if (pf) {
            if constexpr (IN_F16) {
#pragma unroll
                for (int k = 0; k < CPT; ++k) {
                    const int cc = tid + k * NT;
                    if (cc < NCH) commit16(1 - pb, cc, xr16[k]);
                }
            } else {
#pragma unroll
                for (int k = 0; k < CPT; ++k) {
                    const int cc = tid + k * NT;
                    if (cc < NCH) commit32(1 - pb, cc, xr32[k]);
                }
            }
        }

        barrier_lds_only();
        pb ^= 1;
    }
}

extern "C" void kernel_launch(void* const* d_in, const int* in_sizes, int n_in,
                              void* d_out, int out_size, void* d_ws, size_t ws_size,
                              hipStream_t stream) {
    const float* X     = (const float*)d_in[0];
    const float* w1_ih = (const float*)d_in[1];
    const float* w1_hh = (const float*)d_in[2];
    const float* b1_ih = (const float*)d_in[3];
    const float* b1_hh = (const float*)d_in[4];
    const float* w2_ih = (const float*)d_in[5];
    const float* w2_hh = (const float*)d_in[6];
    const float* b2_ih = (const float*)d_in[7];
    const float* b2_hh = (const float*)d_in[8];
    const float* w3_ih = (const float*)d_in[9];
    const float* w3_hh = (const float*)d_in[10];
    const float* b3_ih = (const float*)d_in[11];
    const float* b3_hh = (const float*)d_in[12];
    const float* w4_ih = (const float*)d_in[13];
    const float* w4_hh = (const float*)d_in[14];
    const float* b4_ih = (const float*)d_in[15];
    const float* b4_hh = (const float*)d_in[16];

    float* out = (float*)d_out;

    // inter-layer staging in f16 (identical values to the f16 recurrence panels;
    // zero added rounding): h1 [512,256,128], h2 [512,256,32], h3 [512,256,128]
    f16* h1 = (f16*)d_ws;
    f16* h2 = h1 + (size_t)T_STEPS * BATCH * 128;
    f16* h3 = h2 + (size_t)T_STEPS * BATCH * 32;

    constexpr int GRID = BATCH / 16;

    // layer 1: 64 -> 128 (fp32 in, f16 staging out)
    lstm_mfma<64, 128, false, true, false><<<GRID, 512, 0, stream>>>(
        X, w1_ih, w1_hh, b1_ih, b1_hh, h1);
    // layer 2: 128 -> 32, bottleneck tanh on forwarded output only
    lstm_mfma<128, 32, true, true, true><<<GRID, 128, 0, stream>>>(
        h1, w2_ih, w2_hh, b2_ih, b2_hh, h2);
    // layer 3: 32 -> 128
    lstm_mfma<32, 128, true, true, false><<<GRID, 512, 0, stream>>>(
        h2, w3_ih, w3_hh, b3_ih, b3_hh, h3);
    // layer 4: 128 -> 64 (f16 in, fp32 final out)
    lstm_mfma<128, 64, true, false, false><<<GRID, 256, 0, stream>>>(
        h3, w4_ih, w4_hh, b4_ih, b4_hh, out);
}